// Round 1
// 170.521 us; speedup vs baseline: 1.0237x; 1.0237x over previous
//
#include <hip/hip_runtime.h>
#include <hip/hip_bf16.h>

#define BB 16
#define CC 256
#define HWN 3136
#define NCG 64
#define NCI 32
#define NPP 784   // 28*28

typedef __attribute__((ext_vector_type(8))) short short8;
typedef __attribute__((ext_vector_type(4))) float floatx4;

__device__ __forceinline__ unsigned short f2bf(float f) {
    union { __hip_bfloat16 h; unsigned short u; } cv;
    cv.h = __float2bfloat16(f);
    return cv.u;
}
__device__ __forceinline__ float bf2f(unsigned short u) {
    return __uint_as_float(((unsigned)u) << 16);
}

// ---------------- kernel H: prep (blocks 0..127) + BN1 partial stats (blocks 128..4223) ----------------
// prep: weights->bf16 (+swizzled w_z image), zero bn2acc/T1g/Gg, pool K-pad.
// stats: per-(b,c) sum/sumsq of x written NON-atomically to bn1part.
__global__ __launch_bounds__(256) void k_head(const float* __restrict__ x,
                                              const float* __restrict__ w_t,
                                              const float* __restrict__ w_p,
                                              const float* __restrict__ w_g,
                                              const float* __restrict__ w_z,
                                              unsigned short* __restrict__ wcat,
                                              unsigned short* __restrict__ wzb,
                                              unsigned short* __restrict__ pool,
                                              float* __restrict__ zacc,
                                              float* __restrict__ bn1part) {
    int blk = blockIdx.x;
    int c = threadIdx.x;
    if (blk < 128) {
        int o = blk;
        const float* src = (o < 32) ? (w_t + o * CC)
                          : (o < 64) ? (w_p + (o - 32) * CC)
                                     : (w_g + (o - 64) * CC);
        wcat[o * CC + c] = f2bf(src[c]);
        {   // w_z: rows 2o, 2o+1 of padded [256][72] image
            int r = o * 2 + (c >> 7);
            int kk = c & 127;
            if (kk < 72)
                wzb[r * 72 + kk] = (kk < 64) ? f2bf(w_z[r * 64 + kk]) : (unsigned short)0;
        }
        if (o < 96) {   // zero pooled K-pad cols 784..799 for channel o, all 16 batches
            int b = c >> 4, kk = c & 15;
            pool[((size_t)(b * 96 + o)) * 800 + 784 + kk] = 0;
        }
        // zero bn2acc(128) + T1g(512) + Gg(16*1024) = 17024 floats, distributed
        int idx = o * 256 + c;
        if (idx < 17024) zacc[idx] = 0.f;
        return;
    }
    int bc = blk - 128;     // b*CC + c
    const float4* p = (const float4*)(x + (size_t)bc * HWN);
    int tid = c;
    float s = 0.f, q = 0.f;
    for (int i = tid; i < 784; i += 256) {
        float4 v = p[i];
        s += v.x + v.y + v.z + v.w;
        q += v.x * v.x + v.y * v.y + v.z * v.z + v.w * v.w;
    }
    #pragma unroll
    for (int off = 32; off > 0; off >>= 1) {
        s += __shfl_down(s, off);
        q += __shfl_down(q, off);
    }
    __shared__ float sh[16];
    int wid = tid >> 6, lane = tid & 63;
    if (lane == 0) { sh[wid] = s; sh[8 + wid] = q; }
    __syncthreads();
    if (tid == 0) bn1part[bc]        = sh[0] + sh[1] + sh[2] + sh[3];
    if (tid == 1) bn1part[4096 + bc] = sh[8] + sh[9] + sh[10] + sh[11];
}

// ---------------- kernel 1: BN1+ReLU+conv1x1 MFMA, fused maxpool + T1 + Gram ----------------
// grid (28,B); 256 thr. M=128 o x N=112 hw; K=256, x prefetched one k-step ahead
// (prefetch issued AFTER the pre-MFMA barrier so its latency hides under the MFMAs).
__global__ __launch_bounds__(256) void k_conv1(const float* __restrict__ x,
                                               const unsigned short* __restrict__ wcat,
                                               const float* __restrict__ bn1part,
                                               const float* __restrict__ gamma,
                                               const float* __restrict__ beta,
                                               const float* __restrict__ b_g,
                                               const float* __restrict__ b_t,
                                               const float* __restrict__ b_p,
                                               unsigned short* __restrict__ th,
                                               unsigned short* __restrict__ pool,
                                               float* __restrict__ T1g,
                                               float* __restrict__ Gg) {
    int b  = blockIdx.y;
    int bx = blockIdx.x;           // 0..27
    int hw0 = bx * 112;
    int tid = threadIdx.x;
    int wv = tid >> 6, ln = tid & 63;
    int col = ln & 15, quad = ln >> 4;

    __shared__ unsigned short smem[128 * 120];   // A|B during K-loop; Ct afterwards
    unsigned short* As = smem;
    unsigned short* Bs = smem + 4096;
    __shared__ float ab_s[512];
    __shared__ float bias_s[128];

    {   // fold BN1 finalize from per-batch partials
        const float inv = 1.0f / (BB * HWN);
        float s = 0.f, q = 0.f;
        #pragma unroll
        for (int b2 = 0; b2 < BB; ++b2) {
            s += bn1part[b2 * 256 + tid];
            q += bn1part[4096 + b2 * 256 + tid];
        }
        float mean = s * inv;
        float var  = q * inv - mean * mean;
        float a = gamma[tid] * rsqrtf(var + 1e-5f);
        ab_s[tid] = a;
        ab_s[CC + tid] = beta[tid] - mean * a;
    }
    if (tid < 128) {
        int o = tid;
        bias_s[o] = (o < 32) ? b_t[o] : (o < 64) ? b_p[o - 32] : b_g[o - 64];
    }
    __syncthreads();

    floatx4 acc[2][7];
    #pragma unroll
    for (int mt = 0; mt < 2; ++mt)
        for (int nt = 0; nt < 7; ++nt)
            acc[mt][nt] = (floatx4){0.f, 0.f, 0.f, 0.f};

    int p   = tid & 15;    // c-pair index
    int hwq = tid >> 4;    // base hw-quad (0..15)
    const float* xb = x + (size_t)(b * CC) * HWN + hw0;
    bool q1 = (hwq + 16) < 28;

    // prefetch k0=0
    float4 pv0[2], pv1[2];
    {
        int c0 = 2 * p;
        pv0[0] = *(const float4*)(xb + (size_t)c0 * HWN + hwq * 4);
        pv1[0] = *(const float4*)(xb + (size_t)(c0 + 1) * HWN + hwq * 4);
        if (q1) {
            pv0[1] = *(const float4*)(xb + (size_t)c0 * HWN + (hwq + 16) * 4);
            pv1[1] = *(const float4*)(xb + (size_t)(c0 + 1) * HWN + (hwq + 16) * 4);
        }
    }

    for (int k0 = 0; k0 < CC; k0 += 32) {
        // stage A (weights) via async global->LDS
        #pragma unroll
        for (int i = 0; i < 2; ++i) {
            int row = wv * 32 + i * 16 + (ln >> 2);
            int q   = ln & 3;
            const unsigned short* gp = wcat + row * CC + k0 + q * 8;
            __builtin_amdgcn_global_load_lds(
                (const __attribute__((address_space(1))) unsigned int*)gp,
                (__attribute__((address_space(3))) unsigned int*)&As[(wv * 2 + i) * 512],
                16, 0, 0);
        }
        // stage B from prefetched regs
        {
            int c0 = k0 + 2 * p;
            float a0 = ab_s[c0],     d0 = ab_s[CC + c0];
            float a1 = ab_s[c0 + 1], d1 = ab_s[CC + c0 + 1];
            unsigned int* bw = (unsigned int*)Bs;
            #pragma unroll
            for (int t = 0; t < 2; ++t) {
                if (t == 0 || q1) {
                    int qi = hwq + 16 * t;
                    float4 v0 = pv0[t], v1 = pv1[t];
                    float r0[4] = { fmaxf(fmaf(a0, v0.x, d0), 0.f), fmaxf(fmaf(a0, v0.y, d0), 0.f),
                                    fmaxf(fmaf(a0, v0.z, d0), 0.f), fmaxf(fmaf(a0, v0.w, d0), 0.f) };
                    float r1[4] = { fmaxf(fmaf(a1, v1.x, d1), 0.f), fmaxf(fmaf(a1, v1.y, d1), 0.f),
                                    fmaxf(fmaf(a1, v1.z, d1), 0.f), fmaxf(fmaf(a1, v1.w, d1), 0.f) };
                    #pragma unroll
                    for (int i = 0; i < 4; ++i) {
                        unsigned int w = (unsigned int)f2bf(r0[i]) | ((unsigned int)f2bf(r1[i]) << 16);
                        bw[(qi * 4 + i) * 16 + p] = w;
                    }
                }
            }
        }
        __syncthreads();   // drains A-DMA only; x prefetch goes below so MFMAs cover it

        // prefetch next k-step's x (latency hidden under MFMA phase)
        if (k0 + 32 < CC) {
            int c0 = k0 + 32 + 2 * p;
            pv0[0] = *(const float4*)(xb + (size_t)c0 * HWN + hwq * 4);
            pv1[0] = *(const float4*)(xb + (size_t)(c0 + 1) * HWN + hwq * 4);
            if (q1) {
                pv0[1] = *(const float4*)(xb + (size_t)c0 * HWN + (hwq + 16) * 4);
                pv1[1] = *(const float4*)(xb + (size_t)(c0 + 1) * HWN + (hwq + 16) * 4);
            }
        }

        short8 af0 = *(const short8*)&As[(wv * 32 +      col) * 32 + quad * 8];
        short8 af1 = *(const short8*)&As[(wv * 32 + 16 + col) * 32 + quad * 8];
        #pragma unroll
        for (int nt = 0; nt < 7; ++nt) {
            short8 bf = *(const short8*)&Bs[(nt * 16 + col) * 32 + quad * 8];
            acc[0][nt] = __builtin_amdgcn_mfma_f32_16x16x32_bf16(af0, bf, acc[0][nt], 0, 0, 0);
            acc[1][nt] = __builtin_amdgcn_mfma_f32_16x16x32_bf16(af1, bf, acc[1][nt], 0, 0, 0);
        }
        __syncthreads();
    }

    // ---- stage C (with bias) to LDS ----
    unsigned short* Ct = smem;    // [128][120]
    #pragma unroll
    for (int mt = 0; mt < 2; ++mt) {
        int obase = wv * 32 + mt * 16 + quad * 4;
        #pragma unroll
        for (int r = 0; r < 4; ++r) {
            float bias = bias_s[obase + r];
            #pragma unroll
            for (int nt = 0; nt < 7; ++nt)
                Ct[(obase + r) * 120 + nt * 16 + col] = f2bf(acc[mt][nt][r] + bias);
        }
    }
    __syncthreads();

    // ---- theta (ch 0..31): full-res vectorized store ----
    #pragma unroll
    for (int i = 0; i < 4; ++i) {
        int e = tid + i * 256;     // 896 = 32ch x 28 col4
        if (e < 896) {
            int ch = e / 28, c4 = e - ch * 28;
            ushort4 v = *(const ushort4*)&Ct[ch * 120 + c4 * 4];
            *(ushort4*)&th[((size_t)(b * NCI + ch)) * HWN + hw0 + c4 * 4] = v;
        }
    }
    // ---- T1: per-batch theta row sums ----
    {
        int row = tid >> 3;      // 0..31
        int seg = tid & 7;       // 0..7
        float s = 0.f;
        #pragma unroll
        for (int j = 0; j < 14; ++j) s += bf2f(Ct[row * 120 + seg * 14 + j]);
        s += __shfl_down(s, 4);
        s += __shfl_down(s, 2);
        s += __shfl_down(s, 1);
        if (seg == 0) atomicAdd(&T1g[b * NCI + row], s);
    }
    // ---- Gram: theta.theta^T over this tile's 112 hw (K=112 = 3x32 + masked 16) ----
    {
        int m = wv >> 1, n = wv & 1;   // 4 waves cover the 2x2 quadrants of 32x32
        floatx4 g = (floatx4){0.f, 0.f, 0.f, 0.f};
        short8 z8 = (short8){0, 0, 0, 0, 0, 0, 0, 0};
        #pragma unroll
        for (int ks = 0; ks < 4; ++ks) {
            short8 ga, gb;
            if (ks < 3 || quad < 2) {   // k = ks*32 + quad*8 .. +7 must be < 112
                ga = *(const short8*)&Ct[(m * 16 + col) * 120 + ks * 32 + quad * 8];
                gb = *(const short8*)&Ct[(n * 16 + col) * 120 + ks * 32 + quad * 8];
            } else {
                ga = z8; gb = z8;
            }
            g = __builtin_amdgcn_mfma_f32_16x16x32_bf16(ga, gb, g, 0, 0, 0);
        }
        float* gg = Gg + b * 1024 + (m * 16 + quad * 4) * 32 + n * 16 + col;
        #pragma unroll
        for (int r = 0; r < 4; ++r) atomicAdd(&gg[r * 32], g[r]);
    }
    // ---- phi/g (ch 32..127): 2x2 maxpool -> pool[b][ch-32][bx*28 + m] ----
    #pragma unroll
    for (int i = 0; i < 11; ++i) {
        int e = tid + i * 256;     // 2688 = 96ch x 28 m
        if (e < 2688) {
            int ch = e / 28, m = e - ch * 28;
            const unsigned short* r0p = &Ct[(32 + ch) * 120 + 2 * m];
            float v = fmaxf(fmaxf(bf2f(r0p[0]), bf2f(r0p[1])),
                            fmaxf(bf2f(r0p[56]), bf2f(r0p[57])));
            pool[((size_t)(b * 96 + ch)) * 800 + bx * 28 + m] = f2bf(v);
        }
    }
}

// ---------------- kernel 3: S = g.phi^T/Np (all 8 waves) + BN2 stats from precomputed Gram ----------------
// grid (16); 512 thr. Emits Sg (bf16, [cg][ci] rows 40, pre-scaled) and complete bn2acc.
__global__ __launch_bounds__(512) void k_sgemm(const unsigned short* __restrict__ pool,
                                               const float* __restrict__ T1g,
                                               const float* __restrict__ Gg,
                                               unsigned short* __restrict__ Sg,
                                               float* __restrict__ bn2acc) {
    int b = blockIdx.x;
    int tid = threadIdx.x;
    int wv = tid >> 6, ln = tid & 63;
    int col = ln & 15, quad = ln >> 4;
    __shared__ float Sred[8 * 2048];
    __shared__ float Gred[1024];
    __shared__ float T1s[32];
    __shared__ float shs[64], shq[64];

    if (tid < 64) { shs[tid] = 0.f; shq[tid] = 0.f; }
    if (tid < 32) T1s[tid] = T1g[b * NCI + tid];
    for (int idx = tid; idx < 1024; idx += 512) Gred[idx] = Gg[b * 1024 + idx];

    const unsigned short* gbase = pool + ((size_t)(b * 96 + 32)) * 800;  // g rows (cg)
    const unsigned short* pbase = pool + ((size_t)(b * 96)) * 800;       // phi rows (ci)
    floatx4 acc[4][2];
    #pragma unroll
    for (int mt = 0; mt < 4; ++mt)
        for (int nt = 0; nt < 2; ++nt)
            acc[mt][nt] = (floatx4){0.f, 0.f, 0.f, 0.f};
    for (int s = wv; s < 25; s += 8) {
        int k0 = s * 32;
        short8 af[4], bfr[2];
        #pragma unroll
        for (int mt = 0; mt < 4; ++mt)
            af[mt] = *(const short8*)&gbase[(mt * 16 + col) * 800 + k0 + quad * 8];
        #pragma unroll
        for (int nt = 0; nt < 2; ++nt)
            bfr[nt] = *(const short8*)&pbase[(nt * 16 + col) * 800 + k0 + quad * 8];
        #pragma unroll
        for (int mt = 0; mt < 4; ++mt)
            #pragma unroll
            for (int nt = 0; nt < 2; ++nt)
                acc[mt][nt] = __builtin_amdgcn_mfma_f32_16x16x32_bf16(af[mt], bfr[nt], acc[mt][nt], 0, 0, 0);
    }
    #pragma unroll
    for (int mt = 0; mt < 4; ++mt)
        for (int nt = 0; nt < 2; ++nt)
            for (int r = 0; r < 4; ++r) {
                int cg = mt * 16 + quad * 4 + r;
                int ci = nt * 16 + col;
                Sred[wv * 2048 + cg * 32 + ci] = acc[mt][nt][r];
            }
    __syncthreads();

    // reduce S -> Sg global (bf16) + Sf (bf16-rounded f32) in place
    for (int idx = tid; idx < 2048; idx += 512) {
        float s = 0.f;
        #pragma unroll
        for (int w = 0; w < 8; ++w) s += Sred[w * 2048 + idx];
        int cg = idx >> 5, ci = idx & 31;
        unsigned short h = f2bf(s * (1.0f / NPP));
        Sg[(size_t)b * 2560 + cg * 40 + ci] = h;
        Sred[idx] = bf2f(h);
    }
    __syncthreads();

    // BN2 stats: sum = S.T1, sumsq = s^T G s ; 512 thr: cg x 8 ci-parts
    {
        int cg = tid & 63, part = tid >> 6;
        float sum = 0.f, sq = 0.f;
        #pragma unroll
        for (int i = 0; i < 4; ++i) {
            int ci = part * 4 + i;
            float sv = Sred[cg * 32 + ci];
            sum += sv * T1s[ci];
            float t = 0.f;
            #pragma unroll
            for (int cj = 0; cj < 32; ++cj)
                t += Gred[ci * 32 + cj] * Sred[cg * 32 + cj];
            sq += sv * t;
        }
        atomicAdd(&shs[cg], sum);
        atomicAdd(&shq[cg], sq);
    }
    __syncthreads();
    if (tid < 64) {
        atomicAdd(&bn2acc[tid], shs[tid]);
        atomicAdd(&bn2acc[64 + tid], shq[tid]);
    }
}

// ---------------- kernel 4: recompute y-tile + BN2+ReLU + conv1x1(z) + residual ----------------
// grid (49,B); 256 thr. M=64 hw x N=256 co (full width, no z-split), K=64.
__global__ __launch_bounds__(256) void k_convz(const unsigned short* __restrict__ th,
                                               const unsigned short* __restrict__ Sg,
                                               const unsigned short* __restrict__ wzb,
                                               const float* __restrict__ bn2acc,
                                               const float* __restrict__ gamma,
                                               const float* __restrict__ beta,
                                               const float* __restrict__ b_z,
                                               const float* __restrict__ x,
                                               float* __restrict__ out) {
    int b = blockIdx.y;
    int hw0 = blockIdx.x * 64;
    int tid = threadIdx.x;
    int wv = tid >> 6, ln = tid & 63;
    int col = ln & 15, quad = ln >> 4;

    __shared__ unsigned short Wl[256 * 72];  // full weight image (36 KB)
    __shared__ unsigned short TS[5120];      // Tt[64*40] + St[64*40]; Yt[64*72] overlays later
    __shared__ float ab2_s[128];
    unsigned short* Tt = TS;
    unsigned short* St = TS + 2560;
    unsigned short* Yt = TS;

    // W DMA: 36 chunks of 1 KB from pre-swizzled padded image
    for (int j = wv; j < 36; j += 4) {
        const unsigned short* gp = wzb + j * 512 + ln * 8;
        __builtin_amdgcn_global_load_lds(
            (const __attribute__((address_space(1))) unsigned int*)gp,
            (__attribute__((address_space(3))) unsigned int*)&Wl[j * 512],
            16, 0, 0);
    }
    if (tid < 64) {   // BN2 finalize
        const float inv = 1.0f / (BB * HWN);
        float mean = bn2acc[tid] * inv;
        float var  = bn2acc[64 + tid] * inv - mean * mean;
        float a = gamma[tid] * rsqrtf(var + 1e-5f);
        ab2_s[tid] = a;
        ab2_s[64 + tid] = beta[tid] - mean * a;
    }
    {   // stage St flat (bf16 S, pre-scaled)
        const unsigned int* sgw = (const unsigned int*)(Sg + (size_t)b * 2560);
        unsigned int* stw = (unsigned int*)St;
        for (int i = tid; i < 1280; i += 256) stw[i] = sgw[i];
    }
    {   // stage theta transposed: Tt[hw][ci]
        int p2 = tid & 15, hwq = tid >> 4;
        int c0 = 2 * p2;
        const unsigned short* tb = th + (size_t)(b * NCI) * HWN + hw0 + hwq * 4;
        ushort4 v0 = *(const ushort4*)(tb + (size_t)c0 * HWN);
        ushort4 v1 = *(const ushort4*)(tb + (size_t)(c0 + 1) * HWN);
        unsigned int* tw = (unsigned int*)Tt;
        tw[(hwq * 4 + 0) * 20 + p2] = (unsigned)v0.x | ((unsigned)v1.x << 16);
        tw[(hwq * 4 + 1) * 20 + p2] = (unsigned)v0.y | ((unsigned)v1.y << 16);
        tw[(hwq * 4 + 2) * 20 + p2] = (unsigned)v0.z | ((unsigned)v1.z << 16);
        tw[(hwq * 4 + 3) * 20 + p2] = (unsigned)v0.w | ((unsigned)v1.w << 16);
    }
    __syncthreads();

    // recompute y tile: y[hw][cg]
    short8 afy = *(const short8*)&Tt[(wv * 16 + col) * 40 + quad * 8];
    floatx4 yacc[4];
    #pragma unroll
    for (int nt = 0; nt < 4; ++nt) {
        short8 bf = *(const short8*)&St[(nt * 16 + col) * 40 + quad * 8];
        floatx4 z = (floatx4){0.f, 0.f, 0.f, 0.f};
        yacc[nt] = __builtin_amdgcn_mfma_f32_16x16x32_bf16(afy, bf, z, 0, 0, 0);
    }
    __syncthreads();   // all Tt/St reads done before Yt overlay

    // BN2+ReLU + scatter to Yt[hw][cg]
    #pragma unroll
    for (int nt = 0; nt < 4; ++nt) {
        int cg = nt * 16 + col;
        float a = ab2_s[cg], d = ab2_s[64 + cg];
        #pragma unroll
        for (int r = 0; r < 4; ++r) {
            int hwl = wv * 16 + quad * 4 + r;
            Yt[hwl * 72 + cg] = f2bf(fmaxf(fmaf(a, yacc[nt][r], d), 0.f));
        }
    }
    __syncthreads();

    floatx4 acc[16];
    #pragma unroll
    for (int nt = 0; nt < 16; ++nt) acc[nt] = (floatx4){0.f, 0.f, 0.f, 0.f};

    #pragma unroll
    for (int kk = 0; kk < 2; ++kk) {
        short8 afm = *(const short8*)&Yt[(wv * 16 + col) * 72 + kk * 32 + quad * 8];
        #pragma unroll
        for (int nt = 0; nt < 16; ++nt) {
            short8 bf = *(const short8*)&Wl[(nt * 16 + col) * 72 + kk * 32 + quad * 8];
            acc[nt] = __builtin_amdgcn_mfma_f32_16x16x32_bf16(afm, bf, acc[nt], 0, 0, 0);
        }
    }

    #pragma unroll
    for (int nt = 0; nt < 16; ++nt) {
        int co = nt * 16 + col;
        size_t base = ((size_t)(b * CC + co)) * HWN + hw0 + wv * 16 + quad * 4;
        float4 xv = *(const float4*)&x[base];
        float bz = b_z[co];
        float4 r = make_float4(acc[nt][0] + bz + xv.x, acc[nt][1] + bz + xv.y,
                               acc[nt][2] + bz + xv.z, acc[nt][3] + bz + xv.w);
        *(float4*)&out[base] = r;
    }
}

extern "C" void kernel_launch(void* const* d_in, const int* in_sizes, int n_in,
                              void* d_out, int out_size, void* d_ws, size_t ws_size,
                              hipStream_t stream) {
    (void)in_sizes; (void)n_in; (void)out_size; (void)ws_size;
    const float* x   = (const float*)d_in[0];
    const float* g1  = (const float*)d_in[1];
    const float* b1  = (const float*)d_in[2];
    const float* w_g = (const float*)d_in[3];
    const float* b_g = (const float*)d_in[4];
    const float* w_t = (const float*)d_in[5];
    const float* b_t = (const float*)d_in[6];
    const float* w_p = (const float*)d_in[7];
    const float* b_p = (const float*)d_in[8];
    const float* g2  = (const float*)d_in[9];
    const float* b2  = (const float*)d_in[10];
    const float* w_z = (const float*)d_in[11];
    const float* b_z = (const float*)d_in[12];
    float* out = (float*)d_out;

    float* ws      = (float*)d_ws;
    float* bn1part = ws;                                      // 8192  (16 batches x 256 ch x {sum,sq})
    float* zacc    = ws + 8192;                               // bn2acc(128)+T1g(512)+Gg(16384) = 17024
    float* bn2acc  = ws + 8192;                               // 128
    float* T1g     = ws + 8320;                               // 512
    float* Gg      = ws + 8832;                               // 16*1024
    unsigned short* wcat = (unsigned short*)(ws + 25216);     // 32768 shorts
    unsigned short* wzb  = (unsigned short*)(ws + 41600);     // 18432 shorts
    unsigned short* th   = (unsigned short*)(ws + 50816);     // 1605632 shorts
    unsigned short* pool = (unsigned short*)(ws + 853632);    // 1228800 shorts
    unsigned short* Sg   = (unsigned short*)(ws + 1468032);   // 40960 shorts

    k_head  <<<dim3(4224),     dim3(256), 0, stream>>>(x, w_t, w_p, w_g, w_z, wcat, wzb, pool, zacc, bn1part);
    k_conv1 <<<dim3(28, BB),   dim3(256), 0, stream>>>(x, wcat, bn1part, g1, b1, b_g, b_t, b_p, th, pool, T1g, Gg);
    k_sgemm <<<dim3(BB),       dim3(512), 0, stream>>>(pool, T1g, Gg, Sg, bn2acc);
    k_convz <<<dim3(49, BB),   dim3(256), 0, stream>>>(th, Sg, wzb, bn2acc, g2, b2, b_z, x, out);
}